// Round 3
// baseline (668.990 us; speedup 1.0000x reference)
//
#include <hip/hip_runtime.h>

#define DF 64
#define NB 1024     // dst-range buckets; gather_bucket gets 4 blocks/CU
#define BSTR 1792   // pairs per bucket (avg 1562, sd ~40 -> +5.8 sigma; ovf exact)
#define NPB 98      // max nodes per bucket (ceil(100000/1024)=98)
#define APAD 65     // LDS accumulator row stride in words (64+1, de-banks)

typedef __attribute__((ext_vector_type(8))) short bf16x8;  // MFMA A/B frag
typedef __attribute__((ext_vector_type(4))) float f32x4;   // MFMA C/D frag

__device__ __forceinline__ unsigned short bf16rne(float f) {
    unsigned u = __float_as_uint(f);
    unsigned r = u + 0x7fffu + ((u >> 16) & 1u);
    return (unsigned short)(r >> 16);
}
__device__ __forceinline__ float b2f(unsigned short u) {
    return __uint_as_float((unsigned)u << 16);
}

// ---------------------------------------------------------------------------
// K1: h (fp32) -> hbs row-major bf16 [N][64]. Also zeroes bucket cursors +
// ovfcnt. Row-major is what both the bucket-gather (full-line per edge) and
// K4's MFMA A-fragments want.
// ---------------------------------------------------------------------------
__global__ __launch_bounds__(256) void conv_zero(
    const float* __restrict__ h, unsigned short* __restrict__ hbs,
    int* __restrict__ gcur, int* __restrict__ ovfcnt, int N)
{
    int tid = blockIdx.x * 256 + threadIdx.x;
    if (tid < NB) gcur[tid] = 0;
    if (tid == NB) *ovfcnt = 0;
    if (tid < N * 8) {
        int n = tid >> 3, f8 = tid & 7;
        const float* hp = &h[(size_t)n * DF + f8 * 8];
        float4 v0 = *(const float4*)hp;
        float4 v1 = *(const float4*)(hp + 4);
        ushort4 o0, o1;
        o0.x = bf16rne(v0.x); o0.y = bf16rne(v0.y); o0.z = bf16rne(v0.z); o0.w = bf16rne(v0.w);
        o1.x = bf16rne(v1.x); o1.y = bf16rne(v1.y); o1.z = bf16rne(v1.z); o1.w = bf16rne(v1.w);
        unsigned short* op = &hbs[(size_t)n * DF + f8 * 8];
        *(ushort4*)op = o0;
        *(ushort4*)(op + 4) = o1;
    }
}

// ---------------------------------------------------------------------------
// K2a: bin edges into NB dst-range buckets. Per block: LDS histogram ->
// one global atomicAdd per NON-EMPTY bucket (rotated start order) reserves
// an EXCLUSIVE span -> packed u32 (local_node<<17 | src) written into it.
// ---------------------------------------------------------------------------
#define EPT 13  // edges per thread; per block = 13*256 = 3328
__global__ __launch_bounds__(256) void bin_edges(
    const int* __restrict__ src, const int* __restrict__ dst,
    int* __restrict__ gcur, unsigned* __restrict__ pairs,
    int* __restrict__ ovf, int* __restrict__ ovfcnt, int ovfcap, int E, int N)
{
    __shared__ unsigned hist[NB];
    __shared__ unsigned base_s[NB];
    int t = threadIdx.x;
    for (int i = t; i < NB; i += 256) hist[i] = 0;
    __syncthreads();

    int e0 = blockIdx.x * (EPT * 256);
    unsigned pk[EPT];
    #pragma unroll
    for (int k = 0; k < EPT; ++k) {
        int e = e0 + k * 256 + t;
        pk[k] = 0xFFFFFFFFu;
        if (e < E) {
            int d = dst[e];
            unsigned bkt = (unsigned)(((unsigned long long)d * NB) / (unsigned)N);
            unsigned r = atomicAdd(&hist[bkt], 1u);
            pk[k] = (r << 10) | bkt;   // rank < 3328 fits in 12 bits; bkt in 10
        }
    }
    __syncthreads();
    int rot = (blockIdx.x * 67) & (NB - 1);   // de-phase blocks' atomic order
    for (int i = t; i < NB; i += 256) {
        int ii = (i + rot) & (NB - 1);
        unsigned hv = hist[ii];
        if (hv) base_s[ii] = (unsigned)atomicAdd(&gcur[ii], (int)hv);
    }
    __syncthreads();

    #pragma unroll
    for (int k = 0; k < EPT; ++k) {
        if (pk[k] != 0xFFFFFFFFu) {
            int e = e0 + k * 256 + t;
            int d = dst[e], s = src[e];   // re-read (L1/L2 warm)
            unsigned bkt = pk[k] & (NB - 1u);
            unsigned pos = base_s[bkt] + (pk[k] >> 10);
            if (pos < BSTR) {
                int lo = (int)(((long long)bkt * N + NB - 1) / NB);
                pairs[(size_t)bkt * BSTR + pos] = ((unsigned)(d - lo) << 17) | (unsigned)s;
            } else {  // bucket span overflow -> exact fallback list
                int p = atomicAdd(ovfcnt, 1);
                if (p < ovfcap) { ovf[2 * p] = d; ovf[2 * p + 1] = s; }
            }
        }
    }
}

// ---------------------------------------------------------------------------
// K2b' (fused build_ell + gather): per bucket, accumulate src rows directly
// into an f32 LDS accumulator [NPB][APAD]. Wave-iter = 8 edges; 8 lanes per
// edge each load 16 B of the src row (the 8 lanes share ONE 128 B line ->
// 1 line request/edge, 4x fewer than the sliced gather). Features added via
// ds_add_f32 (HW LDS float atomics). Exact for ANY degree - no ELL cap, no
// degree overflow path. Writes csum (bf16 raw sum) + cnt (exact deg).
// ---------------------------------------------------------------------------
__global__ __launch_bounds__(512) void gather_bucket(
    const unsigned* __restrict__ pairs, const int* __restrict__ gcur,
    const unsigned short* __restrict__ hbs,
    int* __restrict__ cnt, unsigned short* __restrict__ csum, int N)
{
    __shared__ float acc[NPB * APAD];   // 25.5 KB -> 4 blocks/CU
    __shared__ int cnt_l[NPB];
    int b = blockIdx.x, t = threadIdx.x;
    int lo = (int)(((long long)b * N + NB - 1) / NB);
    int hi = (int)(((long long)(b + 1) * N + NB - 1) / NB);
    if (hi > N) hi = N;
    int nn = hi - lo;

    for (int i = t; i < nn * APAD; i += 512) acc[i] = 0.f;
    for (int i = t; i < nn; i += 512) cnt_l[i] = 0;
    __syncthreads();

    int count = gcur[b]; if (count > BSTR) count = BSTR;
    const unsigned* pb = &pairs[(size_t)b * BSTR];
    const int lane = t & 63, wv = t >> 6;
    const int ew = lane >> 3;       // edge slot within wave-iter (0..7)
    const int f8 = lane & 7;        // 8-feat chunk (16 B of the 128 B row)

    for (int i0 = wv * 8; i0 < count; i0 += 64) {   // 8 waves x 8 edges
        int e = i0 + ew;
        if (e < count) {
            unsigned p = pb[e];
            int ld = (int)(p >> 17);
            int s  = (int)(p & 131071u);
            bf16x8 u = *(const bf16x8*)&hbs[(size_t)s * DF + f8 * 8];
            if (f8 == 0) atomicAdd(&cnt_l[ld], 1);
            float* ap = &acc[ld * APAD + f8 * 8];
            #pragma unroll
            for (int j = 0; j < 8; ++j)
                atomicAdd(&ap[j], b2f((unsigned short)u[j]));
        }
    }
    __syncthreads();

    // writeback: bf16 raw sum, coalesced 16 B stores
    for (int i = t; i < nn * 8; i += 512) {
        int node = i >> 3, fb = (i & 7) * 8;
        const float* ap = &acc[node * APAD + fb];
        bf16x8 o;
        #pragma unroll
        for (int j = 0; j < 8; ++j) o[j] = (short)bf16rne(ap[j]);
        *(bf16x8*)&csum[(size_t)(lo + node) * DF + fb] = o;
    }
    for (int i = t; i < nn; i += 512) cnt[lo + i] = cnt_l[i];
}

// ---------------------------------------------------------------------------
// K4: MFMA update. [N x 128]@[128 x 64] via 16x16x32 bf16. Row-major
// [N][64] hbs/csum: A-frag lane (c,q) reads node n0+c, feats base q*8
// (+32 for the second k-tile of each half).
// ---------------------------------------------------------------------------
__global__ __launch_bounds__(256) void sage_update_mfma(
    const float* __restrict__ h, const float* __restrict__ W,
    const float* __restrict__ b, const int* __restrict__ cnt,
    const unsigned short* __restrict__ hbs,
    const unsigned short* __restrict__ csum,
    const int* __restrict__ ovf, const int* __restrict__ ovfcnt,
    int ovfcap, float* __restrict__ out, int N)
{
    const int lane = threadIdx.x & 63;
    const int wave = threadIdx.x >> 6;
    const int c = lane & 15;
    const int q = lane >> 4;

    bf16x8 bf[4][4];
    #pragma unroll
    for (int nt = 0; nt < 4; ++nt) {
        #pragma unroll
        for (int kt = 0; kt < 4; ++kt) {
            const float* wp = &W[(size_t)(nt * 16 + c) * 128 + kt * 32 + q * 8];
            float4 w0 = *(const float4*)wp;
            float4 w1 = *(const float4*)(wp + 4);
            bf16x8 f;
            f[0] = (short)bf16rne(w0.x); f[1] = (short)bf16rne(w0.y);
            f[2] = (short)bf16rne(w0.z); f[3] = (short)bf16rne(w0.w);
            f[4] = (short)bf16rne(w1.x); f[5] = (short)bf16rne(w1.y);
            f[6] = (short)bf16rne(w1.z); f[7] = (short)bf16rne(w1.w);
            bf[nt][kt] = f;
        }
    }
    float bias[4];
    #pragma unroll
    for (int nt = 0; nt < 4; ++nt) bias[nt] = b[nt * 16 + c];

    int oc = *ovfcnt; if (oc > ovfcap) oc = ovfcap;

    int gwave = blockIdx.x * 4 + wave;
    int nwave = gridDim.x * 4;
    int ntiles = (N + 15) >> 4;

    for (int tile = gwave; tile < ntiles; tile += nwave) {
        int n0 = tile << 4;
        int nm = n0 + c;
        int nmc = nm < N ? nm : N - 1;
        int deg = cnt[nmc];
        int extra = 0;
        if (oc > 0) {
            for (int t = 0; t < oc; ++t)
                if (ovf[2 * t] == nm) extra++;
        }
        int dtot = deg + extra;
        float inv = 1.0f / fmaxf((float)dtot, 1.0f);

        bf16x8 a0 = *(const bf16x8*)&hbs[(size_t)nmc * DF + q * 8];
        bf16x8 a1 = *(const bf16x8*)&hbs[(size_t)nmc * DF + 32 + q * 8];
        bf16x8 a2, a3;
        #pragma unroll
        for (int kc = 0; kc < 2; ++kc) {
            bf16x8 u = *(const bf16x8*)&csum[(size_t)nmc * DF + kc * 32 + q * 8];
            float e[8];
            #pragma unroll
            for (int i = 0; i < 8; ++i) e[i] = b2f((unsigned short)u[i]);
            if (oc > 0) {
                for (int t = 0; t < oc; ++t) {
                    if (ovf[2 * t] == nm) {
                        bf16x8 hu = *(const bf16x8*)&hbs[(size_t)ovf[2 * t + 1] * DF + kc * 32 + q * 8];
                        #pragma unroll
                        for (int i = 0; i < 8; ++i) e[i] += b2f((unsigned short)hu[i]);
                    }
                }
            }
            bf16x8 f;
            #pragma unroll
            for (int i = 0; i < 8; ++i) f[i] = (short)bf16rne(e[i] * inv);
            if (kc == 0) a2 = f; else a3 = f;
        }

        f32x4 acc0 = {bias[0], bias[0], bias[0], bias[0]};
        f32x4 acc1 = {bias[1], bias[1], bias[1], bias[1]};
        f32x4 acc2 = {bias[2], bias[2], bias[2], bias[2]};
        f32x4 acc3 = {bias[3], bias[3], bias[3], bias[3]};
        acc0 = __builtin_amdgcn_mfma_f32_16x16x32_bf16(a0, bf[0][0], acc0, 0, 0, 0);
        acc0 = __builtin_amdgcn_mfma_f32_16x16x32_bf16(a1, bf[0][1], acc0, 0, 0, 0);
        acc0 = __builtin_amdgcn_mfma_f32_16x16x32_bf16(a2, bf[0][2], acc0, 0, 0, 0);
        acc0 = __builtin_amdgcn_mfma_f32_16x16x32_bf16(a3, bf[0][3], acc0, 0, 0, 0);
        acc1 = __builtin_amdgcn_mfma_f32_16x16x32_bf16(a0, bf[1][0], acc1, 0, 0, 0);
        acc1 = __builtin_amdgcn_mfma_f32_16x16x32_bf16(a1, bf[1][1], acc1, 0, 0, 0);
        acc1 = __builtin_amdgcn_mfma_f32_16x16x32_bf16(a2, bf[1][2], acc1, 0, 0, 0);
        acc1 = __builtin_amdgcn_mfma_f32_16x16x32_bf16(a3, bf[1][3], acc1, 0, 0, 0);
        acc2 = __builtin_amdgcn_mfma_f32_16x16x32_bf16(a0, bf[2][0], acc2, 0, 0, 0);
        acc2 = __builtin_amdgcn_mfma_f32_16x16x32_bf16(a1, bf[2][1], acc2, 0, 0, 0);
        acc2 = __builtin_amdgcn_mfma_f32_16x16x32_bf16(a2, bf[2][2], acc2, 0, 0, 0);
        acc2 = __builtin_amdgcn_mfma_f32_16x16x32_bf16(a3, bf[2][3], acc2, 0, 0, 0);
        acc3 = __builtin_amdgcn_mfma_f32_16x16x32_bf16(a0, bf[3][0], acc3, 0, 0, 0);
        acc3 = __builtin_amdgcn_mfma_f32_16x16x32_bf16(a1, bf[3][1], acc3, 0, 0, 0);
        acc3 = __builtin_amdgcn_mfma_f32_16x16x32_bf16(a2, bf[3][2], acc3, 0, 0, 0);
        acc3 = __builtin_amdgcn_mfma_f32_16x16x32_bf16(a3, bf[3][3], acc3, 0, 0, 0);

        float ss[4];
        #pragma unroll
        for (int r = 0; r < 4; ++r)
            ss[r] = acc0[r] * acc0[r] + acc1[r] * acc1[r]
                  + acc2[r] * acc2[r] + acc3[r] * acc3[r];
        #pragma unroll
        for (int msk = 1; msk <= 8; msk <<= 1) {
            ss[0] += __shfl_xor(ss[0], msk);
            ss[1] += __shfl_xor(ss[1], msk);
            ss[2] += __shfl_xor(ss[2], msk);
            ss[3] += __shfl_xor(ss[3], msk);
        }
        #pragma unroll
        for (int r = 0; r < 4; ++r) {
            int nr = n0 + q * 4 + r;
            int dr = __shfl(deg + extra, q * 4 + r);
            if (nr < N) {
                float rin = 1.0f / fmaxf(sqrtf(ss[r]), 1e-12f);
                const float* hp = &h[(size_t)nr * DF + c];
                float hv0 = hp[0], hv1 = hp[16], hv2 = hp[32], hv3 = hp[48];
                bool up = dr > 0;
                float o0 = hv0 + (up ? fmaxf(acc0[r] * rin, 0.f) : hv0);
                float o1 = hv1 + (up ? fmaxf(acc1[r] * rin, 0.f) : hv1);
                float o2 = hv2 + (up ? fmaxf(acc2[r] * rin, 0.f) : hv2);
                float o3 = hv3 + (up ? fmaxf(acc3[r] * rin, 0.f) : hv3);
                float* op = &out[(size_t)nr * DF + c];
                op[0] = o0; op[16] = o1; op[32] = o2; op[48] = o3;
            }
        }
    }
}

extern "C" void kernel_launch(void* const* d_in, const int* in_sizes, int n_in,
                              void* d_out, int out_size, void* d_ws, size_t ws_size,
                              hipStream_t stream) {
    const float* h   = (const float*)d_in[0];
    const float* W   = (const float*)d_in[1];
    const float* b   = (const float*)d_in[2];
    const int*   src = (const int*)d_in[3];
    const int*   dst = (const int*)d_in[4];
    float* out = (float*)d_out;

    const int N = in_sizes[0] / DF;
    const int E = in_sizes[3];

    // workspace carve (16B-aligned)
    int* cnt    = (int*)d_ws;                               // N
    int* ovfcnt = cnt + N;                                  // 1
    int* gcur   = cnt + ((N + 31) & ~15);                   // NB
    unsigned short* hbs  = (unsigned short*)(gcur + ((NB + 15) & ~15));  // N*64 bf16
    unsigned short* csum = hbs + (((size_t)N * DF + 15) & ~(size_t)15);  // N*64 bf16
    unsigned* pairs = (unsigned*)(csum + (((size_t)N * DF + 15) & ~(size_t)15));
    int* ovf    = (int*)(pairs + (size_t)NB * BSTR);
    size_t used = (size_t)((char*)ovf - (char*)d_ws);
    int ovfcap  = (ws_size > used + 64) ? (int)((ws_size - used) / 8 - 4) : 0;

    // K1: bf16 row-major conversion + cursor zeroing
    conv_zero<<<(N * 8 + 255) / 256, 256, 0, stream>>>(h, hbs, gcur, ovfcnt, N);

    // K2a: bin edges into dst-range buckets (streaming writes)
    bin_edges<<<(E + EPT * 256 - 1) / (EPT * 256), 256, 0, stream>>>(
        src, dst, gcur, pairs, ovf, ovfcnt, ovfcap, E, N);

    // K2b': fused bucket gather-accumulate (LDS f32 atomics, exact degree)
    gather_bucket<<<NB, 512, 0, stream>>>(pairs, gcur, hbs, cnt, csum, N);

    // K4: MFMA update
    sage_update_mfma<<<512, 256, 0, stream>>>(
        h, W, b, cnt, hbs, csum, ovf, ovfcnt, ovfcap, out, N);
}

// Round 4
// 207.540 us; speedup vs baseline: 3.2234x; 3.2234x over previous
//
#include <hip/hip_runtime.h>

#define DF 64
#define ELLK 32     // per-node ELL width; ovf list handles deg>32 exactly
#define NB 1024     // dst-range buckets; build_gather gets 4 blocks/CU
#define BSTR 1792   // pairs per bucket (avg 1562, sd ~40 -> +5.8 sigma; ovf exact)
#define NPB 98      // max nodes per bucket (ceil(100000/1024)=98)

typedef __attribute__((ext_vector_type(8))) short bf16x8;  // MFMA A/B frag
typedef __attribute__((ext_vector_type(4))) float f32x4;   // MFMA C/D frag

__device__ __forceinline__ unsigned short bf16rne(float f) {
    unsigned u = __float_as_uint(f);
    unsigned r = u + 0x7fffu + ((u >> 16) & 1u);
    return (unsigned short)(r >> 16);
}
__device__ __forceinline__ float b2f(unsigned short u) {
    return __uint_as_float((unsigned)u << 16);
}

// ---------------------------------------------------------------------------
// K1: h (fp32) -> hbs row-major bf16 [(N+1)][64]; row N is a ZERO sentinel
// (gather clamps invalid ELL slots to it). Also zeroes cursors + ovfcnt.
// ---------------------------------------------------------------------------
__global__ __launch_bounds__(256) void conv_zero(
    const float* __restrict__ h, unsigned short* __restrict__ hbs,
    int* __restrict__ gcur, int* __restrict__ ovfcnt, int N)
{
    int tid = blockIdx.x * 256 + threadIdx.x;
    if (tid < NB) gcur[tid] = 0;
    if (tid == NB) *ovfcnt = 0;
    if (tid < (N + 1) * 8) {
        int n = tid >> 3, f8 = tid & 7;
        unsigned short* op = &hbs[(size_t)n * DF + f8 * 8];
        if (n == N) {
            ushort4 z = {0, 0, 0, 0};
            *(ushort4*)op = z; *(ushort4*)(op + 4) = z;
        } else {
            const float* hp = &h[(size_t)n * DF + f8 * 8];
            float4 v0 = *(const float4*)hp;
            float4 v1 = *(const float4*)(hp + 4);
            ushort4 o0, o1;
            o0.x = bf16rne(v0.x); o0.y = bf16rne(v0.y); o0.z = bf16rne(v0.z); o0.w = bf16rne(v0.w);
            o1.x = bf16rne(v1.x); o1.y = bf16rne(v1.y); o1.z = bf16rne(v1.z); o1.w = bf16rne(v1.w);
            *(ushort4*)op = o0;
            *(ushort4*)(op + 4) = o1;
        }
    }
}

// ---------------------------------------------------------------------------
// K2a: bin edges into NB dst-range buckets. Per block: LDS histogram ->
// one global atomicAdd per NON-EMPTY bucket (rotated start order) reserves
// an EXCLUSIVE span -> packed u32 (local_node<<17 | src) written into it.
// ---------------------------------------------------------------------------
#define EPT 13  // edges per thread; per block = 13*256 = 3328
__global__ __launch_bounds__(256) void bin_edges(
    const int* __restrict__ src, const int* __restrict__ dst,
    int* __restrict__ gcur, unsigned* __restrict__ pairs,
    int* __restrict__ ovf, int* __restrict__ ovfcnt, int ovfcap, int E, int N)
{
    __shared__ unsigned hist[NB];
    __shared__ unsigned base_s[NB];
    int t = threadIdx.x;
    for (int i = t; i < NB; i += 256) hist[i] = 0;
    __syncthreads();

    int e0 = blockIdx.x * (EPT * 256);
    unsigned pk[EPT];
    #pragma unroll
    for (int k = 0; k < EPT; ++k) {
        int e = e0 + k * 256 + t;
        pk[k] = 0xFFFFFFFFu;
        if (e < E) {
            int d = dst[e];
            unsigned bkt = (unsigned)(((unsigned long long)d * NB) / (unsigned)N);
            unsigned r = atomicAdd(&hist[bkt], 1u);
            pk[k] = (r << 10) | bkt;   // rank < 3328 fits in 12 bits; bkt in 10
        }
    }
    __syncthreads();
    int rot = (blockIdx.x * 67) & (NB - 1);   // de-phase blocks' atomic order
    for (int i = t; i < NB; i += 256) {
        int ii = (i + rot) & (NB - 1);
        unsigned hv = hist[ii];
        if (hv) base_s[ii] = (unsigned)atomicAdd(&gcur[ii], (int)hv);
    }
    __syncthreads();

    #pragma unroll
    for (int k = 0; k < EPT; ++k) {
        if (pk[k] != 0xFFFFFFFFu) {
            int e = e0 + k * 256 + t;
            int d = dst[e], s = src[e];   // re-read (L1/L2 warm)
            unsigned bkt = pk[k] & (NB - 1u);
            unsigned pos = base_s[bkt] + (pk[k] >> 10);
            if (pos < BSTR) {
                int lo = (int)(((long long)bkt * N + NB - 1) / NB);
                pairs[(size_t)bkt * BSTR + pos] = ((unsigned)(d - lo) << 17) | (unsigned)s;
            } else {  // bucket span overflow -> exact fallback list
                int p = atomicAdd(ovfcnt, 1);
                if (p < ovfcap) { ovf[2 * p] = d; ovf[2 * p + 1] = s; }
            }
        }
    }
}

// ---------------------------------------------------------------------------
// K2b (fused build+gather): per bucket, build the ELL entirely in LDS with
// native INT atomics (permuted cols: p(slot)=(slot&7)*4|(slot>>3), so one
// int4 per neighbor-group), then gather WITHOUT touching global ELL:
// wave = 1 node; 64 lanes = 8 neighbors x 8 feat-chunks; each 8-lane group
// loads one neighbor's full 128 B row (1 line request/edge). Register
// accumulation + 3 shfl_xor reduce. Invalid slots clamp to zero row N via
// cndmask; quads 2-3 skipped by WAVE-UNIFORM scalar branches (no per-lane
// exec churn). Writes csum (bf16 raw sum) + cnt (= min(deg, ELLK)).
// ---------------------------------------------------------------------------
__global__ __launch_bounds__(512) void build_gather(
    const unsigned* __restrict__ pairs, const int* __restrict__ gcur,
    const unsigned short* __restrict__ hbs,
    int* __restrict__ cnt, unsigned short* __restrict__ csum,
    int* __restrict__ ovf, int* __restrict__ ovfcnt, int ovfcap, int N)
{
    __shared__ int ell_l[NPB * ELLK];  // 12.5 KB -> 4 blocks/CU, 32 waves/CU
    __shared__ int cnt_l[NPB];
    int b = blockIdx.x, t = threadIdx.x;
    int lo = (int)(((long long)b * N + NB - 1) / NB);
    int hi = (int)(((long long)(b + 1) * N + NB - 1) / NB);
    if (hi > N) hi = N;
    int nn = hi - lo;
    for (int i = t; i < nn; i += 512) cnt_l[i] = 0;
    __syncthreads();

    // ---- build phase (int LDS atomics, proven fast) ----
    int count = gcur[b]; if (count > BSTR) count = BSTR;
    const unsigned* pb = &pairs[(size_t)b * BSTR];
    for (int i = t; i < count; i += 512) {
        unsigned p = pb[i];
        int ld = (int)(p >> 17);
        int s  = (int)(p & 131071u);
        int slot = atomicAdd(&cnt_l[ld], 1);
        if (slot < ELLK) {
            ell_l[ld * ELLK + (((slot & 7) << 2) | (slot >> 3))] = s;  // permuted
        } else {
            int q = atomicAdd(ovfcnt, 1);
            if (q < ovfcap) { ovf[2 * q] = lo + ld; ovf[2 * q + 1] = s; }
        }
    }
    __syncthreads();

    // ---- gather phase: wave = node, 8 lanes/neighbor ----
    const int lane = t & 63, wv = t >> 6;
    const int ew = lane >> 3;   // neighbor slot within quad (0..7)
    const int f8 = lane & 7;    // 16 B feat chunk of the 128 B row

    for (int ld = wv; ld < nn; ld += 8) {
        int cv = cnt_l[ld];
        int m = cv < ELLK ? cv : ELLK;
        int ms = __builtin_amdgcn_readfirstlane(m);  // wave-uniform
        int4 pv = ((const int4*)&ell_l[ld * ELLK])[ew];  // slots {ew,ew+8,ew+16,ew+24}

        int i0 = (ew     < m) ? pv.x : N;
        int i1 = (ew + 8 < m) ? pv.y : N;
        bf16x8 v0 = *(const bf16x8*)&hbs[(size_t)i0 * DF + f8 * 8];
        bf16x8 v1 = *(const bf16x8*)&hbs[(size_t)i1 * DF + f8 * 8];
        bf16x8 v2 = {0,0,0,0,0,0,0,0};
        bf16x8 v3 = {0,0,0,0,0,0,0,0};
        if (ms > 16) {   // scalar branch: skipped for 57% of nodes
            int i2 = (ew + 16 < m) ? pv.z : N;
            v2 = *(const bf16x8*)&hbs[(size_t)i2 * DF + f8 * 8];
            if (ms > 24) {   // skipped for 93% of nodes
                int i3 = (ew + 24 < m) ? pv.w : N;
                v3 = *(const bf16x8*)&hbs[(size_t)i3 * DF + f8 * 8];
            }
        }

        float a[8];
        #pragma unroll
        for (int j = 0; j < 8; ++j)
            a[j] = (b2f((unsigned short)v0[j]) + b2f((unsigned short)v1[j]))
                 + (b2f((unsigned short)v2[j]) + b2f((unsigned short)v3[j]));

        #pragma unroll
        for (int msk = 8; msk <= 32; msk <<= 1) {
            #pragma unroll
            for (int j = 0; j < 8; ++j) a[j] += __shfl_xor(a[j], msk);
        }

        if (ew == 0) {   // lanes 0..7 store the 128 B csum row
            bf16x8 o;
            #pragma unroll
            for (int j = 0; j < 8; ++j) o[j] = (short)bf16rne(a[j]);
            *(bf16x8*)&csum[(size_t)(lo + ld) * DF + f8 * 8] = o;
        }
    }

    for (int i = t; i < nn; i += 512) {
        int c = cnt_l[i];
        cnt[lo + i] = c < ELLK ? c : ELLK;
    }
}

// ---------------------------------------------------------------------------
// K4: MFMA update. [N x 128]@[128 x 64] via 16x16x32 bf16. Row-major
// [*][64] hbs/csum: A-frag lane (c,q) reads node n0+c, feats base q*8
// (+32 for the second k-tile of each half).
// ---------------------------------------------------------------------------
__global__ __launch_bounds__(256) void sage_update_mfma(
    const float* __restrict__ h, const float* __restrict__ W,
    const float* __restrict__ b, const int* __restrict__ cnt,
    const unsigned short* __restrict__ hbs,
    const unsigned short* __restrict__ csum,
    const int* __restrict__ ovf, const int* __restrict__ ovfcnt,
    int ovfcap, float* __restrict__ out, int N)
{
    const int lane = threadIdx.x & 63;
    const int wave = threadIdx.x >> 6;
    const int c = lane & 15;
    const int q = lane >> 4;

    bf16x8 bf[4][4];
    #pragma unroll
    for (int nt = 0; nt < 4; ++nt) {
        #pragma unroll
        for (int kt = 0; kt < 4; ++kt) {
            const float* wp = &W[(size_t)(nt * 16 + c) * 128 + kt * 32 + q * 8];
            float4 w0 = *(const float4*)wp;
            float4 w1 = *(const float4*)(wp + 4);
            bf16x8 f;
            f[0] = (short)bf16rne(w0.x); f[1] = (short)bf16rne(w0.y);
            f[2] = (short)bf16rne(w0.z); f[3] = (short)bf16rne(w0.w);
            f[4] = (short)bf16rne(w1.x); f[5] = (short)bf16rne(w1.y);
            f[6] = (short)bf16rne(w1.z); f[7] = (short)bf16rne(w1.w);
            bf[nt][kt] = f;
        }
    }
    float bias[4];
    #pragma unroll
    for (int nt = 0; nt < 4; ++nt) bias[nt] = b[nt * 16 + c];

    int oc = *ovfcnt; if (oc > ovfcap) oc = ovfcap;

    int gwave = blockIdx.x * 4 + wave;
    int nwave = gridDim.x * 4;
    int ntiles = (N + 15) >> 4;

    for (int tile = gwave; tile < ntiles; tile += nwave) {
        int n0 = tile << 4;
        int nm = n0 + c;
        int nmc = nm < N ? nm : N - 1;
        int deg = cnt[nmc];
        int extra = 0;
        if (oc > 0) {
            for (int t = 0; t < oc; ++t)
                if (ovf[2 * t] == nm) extra++;
        }
        int dtot = deg + extra;
        float inv = 1.0f / fmaxf((float)dtot, 1.0f);

        bf16x8 a0 = *(const bf16x8*)&hbs[(size_t)nmc * DF + q * 8];
        bf16x8 a1 = *(const bf16x8*)&hbs[(size_t)nmc * DF + 32 + q * 8];
        bf16x8 a2, a3;
        #pragma unroll
        for (int kc = 0; kc < 2; ++kc) {
            bf16x8 u = *(const bf16x8*)&csum[(size_t)nmc * DF + kc * 32 + q * 8];
            float e[8];
            #pragma unroll
            for (int i = 0; i < 8; ++i) e[i] = b2f((unsigned short)u[i]);
            if (oc > 0) {
                for (int t = 0; t < oc; ++t) {
                    if (ovf[2 * t] == nm) {
                        bf16x8 hu = *(const bf16x8*)&hbs[(size_t)ovf[2 * t + 1] * DF + kc * 32 + q * 8];
                        #pragma unroll
                        for (int i = 0; i < 8; ++i) e[i] += b2f((unsigned short)hu[i]);
                    }
                }
            }
            bf16x8 f;
            #pragma unroll
            for (int i = 0; i < 8; ++i) f[i] = (short)bf16rne(e[i] * inv);
            if (kc == 0) a2 = f; else a3 = f;
        }

        f32x4 acc0 = {bias[0], bias[0], bias[0], bias[0]};
        f32x4 acc1 = {bias[1], bias[1], bias[1], bias[1]};
        f32x4 acc2 = {bias[2], bias[2], bias[2], bias[2]};
        f32x4 acc3 = {bias[3], bias[3], bias[3], bias[3]};
        acc0 = __builtin_amdgcn_mfma_f32_16x16x32_bf16(a0, bf[0][0], acc0, 0, 0, 0);
        acc0 = __builtin_amdgcn_mfma_f32_16x16x32_bf16(a1, bf[0][1], acc0, 0, 0, 0);
        acc0 = __builtin_amdgcn_mfma_f32_16x16x32_bf16(a2, bf[0][2], acc0, 0, 0, 0);
        acc0 = __builtin_amdgcn_mfma_f32_16x16x32_bf16(a3, bf[0][3], acc0, 0, 0, 0);
        acc1 = __builtin_amdgcn_mfma_f32_16x16x32_bf16(a0, bf[1][0], acc1, 0, 0, 0);
        acc1 = __builtin_amdgcn_mfma_f32_16x16x32_bf16(a1, bf[1][1], acc1, 0, 0, 0);
        acc1 = __builtin_amdgcn_mfma_f32_16x16x32_bf16(a2, bf[1][2], acc1, 0, 0, 0);
        acc1 = __builtin_amdgcn_mfma_f32_16x16x32_bf16(a3, bf[1][3], acc1, 0, 0, 0);
        acc2 = __builtin_amdgcn_mfma_f32_16x16x32_bf16(a0, bf[2][0], acc2, 0, 0, 0);
        acc2 = __builtin_amdgcn_mfma_f32_16x16x32_bf16(a1, bf[2][1], acc2, 0, 0, 0);
        acc2 = __builtin_amdgcn_mfma_f32_16x16x32_bf16(a2, bf[2][2], acc2, 0, 0, 0);
        acc2 = __builtin_amdgcn_mfma_f32_16x16x32_bf16(a3, bf[2][3], acc2, 0, 0, 0);
        acc3 = __builtin_amdgcn_mfma_f32_16x16x32_bf16(a0, bf[3][0], acc3, 0, 0, 0);
        acc3 = __builtin_amdgcn_mfma_f32_16x16x32_bf16(a1, bf[3][1], acc3, 0, 0, 0);
        acc3 = __builtin_amdgcn_mfma_f32_16x16x32_bf16(a2, bf[3][2], acc3, 0, 0, 0);
        acc3 = __builtin_amdgcn_mfma_f32_16x16x32_bf16(a3, bf[3][3], acc3, 0, 0, 0);

        float ss[4];
        #pragma unroll
        for (int r = 0; r < 4; ++r)
            ss[r] = acc0[r] * acc0[r] + acc1[r] * acc1[r]
                  + acc2[r] * acc2[r] + acc3[r] * acc3[r];
        #pragma unroll
        for (int msk = 1; msk <= 8; msk <<= 1) {
            ss[0] += __shfl_xor(ss[0], msk);
            ss[1] += __shfl_xor(ss[1], msk);
            ss[2] += __shfl_xor(ss[2], msk);
            ss[3] += __shfl_xor(ss[3], msk);
        }
        #pragma unroll
        for (int r = 0; r < 4; ++r) {
            int nr = n0 + q * 4 + r;
            int dr = __shfl(deg + extra, q * 4 + r);
            if (nr < N) {
                float rin = 1.0f / fmaxf(sqrtf(ss[r]), 1e-12f);
                const float* hp = &h[(size_t)nr * DF + c];
                float hv0 = hp[0], hv1 = hp[16], hv2 = hp[32], hv3 = hp[48];
                bool up = dr > 0;
                float o0 = hv0 + (up ? fmaxf(acc0[r] * rin, 0.f) : hv0);
                float o1 = hv1 + (up ? fmaxf(acc1[r] * rin, 0.f) : hv1);
                float o2 = hv2 + (up ? fmaxf(acc2[r] * rin, 0.f) : hv2);
                float o3 = hv3 + (up ? fmaxf(acc3[r] * rin, 0.f) : hv3);
                float* op = &out[(size_t)nr * DF + c];
                op[0] = o0; op[16] = o1; op[32] = o2; op[48] = o3;
            }
        }
    }
}

extern "C" void kernel_launch(void* const* d_in, const int* in_sizes, int n_in,
                              void* d_out, int out_size, void* d_ws, size_t ws_size,
                              hipStream_t stream) {
    const float* h   = (const float*)d_in[0];
    const float* W   = (const float*)d_in[1];
    const float* b   = (const float*)d_in[2];
    const int*   src = (const int*)d_in[3];
    const int*   dst = (const int*)d_in[4];
    float* out = (float*)d_out;

    const int N = in_sizes[0] / DF;
    const int E = in_sizes[3];

    // workspace carve (16B-aligned); hbs has N+1 rows (zero sentinel)
    int* cnt    = (int*)d_ws;                               // N
    int* ovfcnt = cnt + N;                                  // 1
    int* gcur   = cnt + ((N + 31) & ~15);                   // NB
    unsigned short* hbs  = (unsigned short*)(gcur + ((NB + 15) & ~15));      // (N+1)*64
    unsigned short* csum = hbs + (((size_t)(N + 1) * DF + 15) & ~(size_t)15); // N*64
    unsigned* pairs = (unsigned*)(csum + (((size_t)N * DF + 15) & ~(size_t)15));
    int* ovf    = (int*)(pairs + (size_t)NB * BSTR);
    size_t used = (size_t)((char*)ovf - (char*)d_ws);
    int ovfcap  = (ws_size > used + 64) ? (int)((ws_size - used) / 8 - 4) : 0;

    // K1: bf16 row-major conversion + zero row + cursor zeroing
    conv_zero<<<((N + 1) * 8 + 255) / 256, 256, 0, stream>>>(h, hbs, gcur, ovfcnt, N);

    // K2a: bin edges into dst-range buckets (streaming writes)
    bin_edges<<<(E + EPT * 256 - 1) / (EPT * 256), 256, 0, stream>>>(
        src, dst, gcur, pairs, ovf, ovfcnt, ovfcap, E, N);

    // K2b: fused LDS-ELL build + row-per-edge gather (register accumulation)
    build_gather<<<NB, 512, 0, stream>>>(
        pairs, gcur, hbs, cnt, csum, ovf, ovfcnt, ovfcap, N);

    // K4: MFMA update
    sage_update_mfma<<<512, 256, 0, stream>>>(
        h, W, b, cnt, hbs, csum, ovf, ovfcnt, ovfcap, out, N);
}

// Round 5
// 199.991 us; speedup vs baseline: 3.3451x; 1.0377x over previous
//
#include <hip/hip_runtime.h>

#define DF 64
#define ELLK 32     // per-node ELL width; ovf list handles deg>32 exactly
#define NBB 256     // BIN buckets (scatter-amp-friendly); ~391 nodes/bucket
#define GQ 4        // gather quarters per bucket -> 1024 gather blocks
#define BSTR 7168   // pairs per bucket (avg 6250, sd ~79 -> 11.6 sigma margin)
#define NPB 98      // nodes per gather quarter (ceil(391/4)=98)

typedef __attribute__((ext_vector_type(8))) short bf16x8;  // MFMA A/B frag
typedef __attribute__((ext_vector_type(4))) float f32x4;   // MFMA C/D frag

__device__ __forceinline__ unsigned short bf16rne(float f) {
    unsigned u = __float_as_uint(f);
    unsigned r = u + 0x7fffu + ((u >> 16) & 1u);
    return (unsigned short)(r >> 16);
}
__device__ __forceinline__ float b2f(unsigned short u) {
    return __uint_as_float((unsigned)u << 16);
}

// ---------------------------------------------------------------------------
// K1: h (fp32) -> hbs row-major bf16 [(N+1)][64]; row N is a ZERO sentinel
// (gather clamps invalid ELL slots to it). Also zeroes cursors + ovfcnt.
// ---------------------------------------------------------------------------
__global__ __launch_bounds__(256) void conv_zero(
    const float* __restrict__ h, unsigned short* __restrict__ hbs,
    int* __restrict__ gcur, int* __restrict__ ovfcnt, int N)
{
    int tid = blockIdx.x * 256 + threadIdx.x;
    if (tid < NBB) gcur[tid] = 0;
    if (tid == NBB) *ovfcnt = 0;
    if (tid < (N + 1) * 8) {
        int n = tid >> 3, f8 = tid & 7;
        unsigned short* op = &hbs[(size_t)n * DF + f8 * 8];
        if (n == N) {
            ushort4 z = {0, 0, 0, 0};
            *(ushort4*)op = z; *(ushort4*)(op + 4) = z;
        } else {
            const float* hp = &h[(size_t)n * DF + f8 * 8];
            float4 v0 = *(const float4*)hp;
            float4 v1 = *(const float4*)(hp + 4);
            ushort4 o0, o1;
            o0.x = bf16rne(v0.x); o0.y = bf16rne(v0.y); o0.z = bf16rne(v0.z); o0.w = bf16rne(v0.w);
            o1.x = bf16rne(v1.x); o1.y = bf16rne(v1.y); o1.z = bf16rne(v1.z); o1.w = bf16rne(v1.w);
            *(ushort4*)op = o0;
            *(ushort4*)(op + 4) = o1;
        }
    }
}

// ---------------------------------------------------------------------------
// K2a: bin edges into NBB=256 dst-range buckets (round-1's proven scatter
// granularity: ~13 pairs/span/block -> ~2.5x write amp, not 6x). Per block:
// LDS histogram -> one global atomicAdd per NON-EMPTY bucket (rotated
// order) reserves an EXCLUSIVE span -> packed u32 (local_node<<17 | src).
// ---------------------------------------------------------------------------
#define EPT 13  // edges per thread; per block = 13*256 = 3328
__global__ __launch_bounds__(256) void bin_edges(
    const int* __restrict__ src, const int* __restrict__ dst,
    int* __restrict__ gcur, unsigned* __restrict__ pairs,
    int* __restrict__ ovf, int* __restrict__ ovfcnt, int ovfcap, int E, int N)
{
    __shared__ unsigned hist[NBB];
    __shared__ unsigned base_s[NBB];
    int t = threadIdx.x;
    if (t < NBB) hist[t] = 0;
    __syncthreads();

    int e0 = blockIdx.x * (EPT * 256);
    unsigned pk[EPT];
    #pragma unroll
    for (int k = 0; k < EPT; ++k) {
        int e = e0 + k * 256 + t;
        pk[k] = 0xFFFFFFFFu;
        if (e < E) {
            int d = dst[e];
            unsigned bkt = (unsigned)(((unsigned long long)d * NBB) / (unsigned)N);
            unsigned r = atomicAdd(&hist[bkt], 1u);
            pk[k] = (r << 8) | bkt;   // rank < 3328 fits in 12 bits; bkt in 8
        }
    }
    __syncthreads();
    int rot = (blockIdx.x * 67) & (NBB - 1);   // de-phase blocks' atomic order
    if (t < NBB) {
        int ii = (t + rot) & (NBB - 1);
        unsigned hv = hist[ii];
        if (hv) base_s[ii] = (unsigned)atomicAdd(&gcur[ii], (int)hv);
    }
    __syncthreads();

    #pragma unroll
    for (int k = 0; k < EPT; ++k) {
        if (pk[k] != 0xFFFFFFFFu) {
            int e = e0 + k * 256 + t;
            int d = dst[e], s = src[e];   // re-read (L1/L2 warm)
            unsigned bkt = pk[k] & (NBB - 1u);
            unsigned pos = base_s[bkt] + (pk[k] >> 8);
            if (pos < BSTR) {
                int lo = (int)(((long long)bkt * N + NBB - 1) / NBB);
                pairs[(size_t)bkt * BSTR + pos] = ((unsigned)(d - lo) << 17) | (unsigned)s;
            } else {  // bucket span overflow -> exact fallback list
                int p = atomicAdd(ovfcnt, 1);
                if (p < ovfcap) { ovf[2 * p] = d; ovf[2 * p + 1] = s; }
            }
        }
    }
}

// ---------------------------------------------------------------------------
// K2b (fused build+gather, quarter-bucket blocks): block = (bucket b =
// blockIdx>>2, quarter qt = blockIdx&3). Scans the bucket's full pairs list
// (4 sibling blocks adjacent in dispatch -> extra reads are L2 hits) and
// FILTERS ld into its 98-node window; inserts into a local LDS ELL with
// native INT atomics (permuted cols). Gather: wave = 1 node; 64 lanes = 8
// neighbors x 8 feat-chunks; each 8-lane group loads one neighbor's full
// 128 B hbs row (1 line request/edge). Register accumulation + 3 shfl_xor.
// Invalid slots clamp to zero row N; quads 2-3 skipped by WAVE-UNIFORM
// scalar branches. Writes csum (bf16 raw sum) + cnt (= min(deg, ELLK)).
// ---------------------------------------------------------------------------
__global__ __launch_bounds__(512) void build_gather(
    const unsigned* __restrict__ pairs, const int* __restrict__ gcur,
    const unsigned short* __restrict__ hbs,
    int* __restrict__ cnt, unsigned short* __restrict__ csum,
    int* __restrict__ ovf, int* __restrict__ ovfcnt, int ovfcap, int N)
{
    __shared__ int ell_l[NPB * ELLK];  // 12.5 KB -> 4 blocks/CU
    __shared__ int cnt_l[NPB];
    int b = blockIdx.x >> 2, qt = blockIdx.x & 3;
    int t = threadIdx.x;
    int lo_b = (int)(((long long)b * N + NBB - 1) / NBB);
    int hi_b = (int)(((long long)(b + 1) * N + NBB - 1) / NBB);
    if (hi_b > N) hi_b = N;
    int nn_b = hi_b - lo_b;
    int q0 = qt * NPB;                       // window [q0, q0+qn) within bucket
    int qn = nn_b - q0; if (qn > NPB) qn = NPB;
    if (qn <= 0) return;                      // (cannot happen at N=100K, safe)
    int nbase = lo_b + q0;                    // first global node of window

    for (int i = t; i < qn; i += 512) cnt_l[i] = 0;
    __syncthreads();

    // ---- build phase: scan bucket pairs, filter to window, int LDS atomics
    int count = gcur[b]; if (count > BSTR) count = BSTR;
    const unsigned* pb = &pairs[(size_t)b * BSTR];
    for (int i = t; i < count; i += 512) {
        unsigned p = pb[i];
        int ld = (int)(p >> 17) - q0;
        if ((unsigned)ld < (unsigned)qn) {
            int s = (int)(p & 131071u);
            int slot = atomicAdd(&cnt_l[ld], 1);
            if (slot < ELLK) {
                ell_l[ld * ELLK + (((slot & 7) << 2) | (slot >> 3))] = s;  // permuted
            } else {
                int q = atomicAdd(ovfcnt, 1);
                if (q < ovfcap) { ovf[2 * q] = nbase + ld; ovf[2 * q + 1] = s; }
            }
        }
    }
    __syncthreads();

    // ---- gather phase: wave = node, 8 lanes/neighbor ----
    const int lane = t & 63, wv = t >> 6;
    const int ew = lane >> 3;   // neighbor slot within quad (0..7)
    const int f8 = lane & 7;    // 16 B feat chunk of the 128 B row

    for (int ld = wv; ld < qn; ld += 8) {
        int cv = cnt_l[ld];
        int m = cv < ELLK ? cv : ELLK;
        int ms = __builtin_amdgcn_readfirstlane(m);  // wave-uniform
        int4 pv = ((const int4*)&ell_l[ld * ELLK])[ew];  // slots {ew,ew+8,ew+16,ew+24}

        int i0 = (ew     < m) ? pv.x : N;
        int i1 = (ew + 8 < m) ? pv.y : N;
        bf16x8 v0 = *(const bf16x8*)&hbs[(size_t)i0 * DF + f8 * 8];
        bf16x8 v1 = *(const bf16x8*)&hbs[(size_t)i1 * DF + f8 * 8];
        bf16x8 v2 = {0,0,0,0,0,0,0,0};
        bf16x8 v3 = {0,0,0,0,0,0,0,0};
        if (ms > 16) {   // scalar branch: skipped for ~57% of nodes
            int i2 = (ew + 16 < m) ? pv.z : N;
            v2 = *(const bf16x8*)&hbs[(size_t)i2 * DF + f8 * 8];
            if (ms > 24) {   // skipped for ~93% of nodes
                int i3 = (ew + 24 < m) ? pv.w : N;
                v3 = *(const bf16x8*)&hbs[(size_t)i3 * DF + f8 * 8];
            }
        }

        float a[8];
        #pragma unroll
        for (int j = 0; j < 8; ++j)
            a[j] = (b2f((unsigned short)v0[j]) + b2f((unsigned short)v1[j]))
                 + (b2f((unsigned short)v2[j]) + b2f((unsigned short)v3[j]));

        #pragma unroll
        for (int msk = 8; msk <= 32; msk <<= 1) {
            #pragma unroll
            for (int j = 0; j < 8; ++j) a[j] += __shfl_xor(a[j], msk);
        }

        if (ew == 0) {   // lanes 0..7 store the 128 B csum row
            bf16x8 o;
            #pragma unroll
            for (int j = 0; j < 8; ++j) o[j] = (short)bf16rne(a[j]);
            *(bf16x8*)&csum[(size_t)(nbase + ld) * DF + f8 * 8] = o;
        }
    }

    for (int i = t; i < qn; i += 512) {
        int c = cnt_l[i];
        cnt[nbase + i] = c < ELLK ? c : ELLK;
    }
}

// ---------------------------------------------------------------------------
// K4: MFMA update. [N x 128]@[128 x 64] via 16x16x32 bf16. Row-major
// [*][64] hbs/csum: A-frag lane (c,q) reads node n0+c, feats base q*8
// (+32 for the second k-tile of each half).
// ---------------------------------------------------------------------------
__global__ __launch_bounds__(256) void sage_update_mfma(
    const float* __restrict__ h, const float* __restrict__ W,
    const float* __restrict__ b, const int* __restrict__ cnt,
    const unsigned short* __restrict__ hbs,
    const unsigned short* __restrict__ csum,
    const int* __restrict__ ovf, const int* __restrict__ ovfcnt,
    int ovfcap, float* __restrict__ out, int N)
{
    const int lane = threadIdx.x & 63;
    const int wave = threadIdx.x >> 6;
    const int c = lane & 15;
    const int q = lane >> 4;

    bf16x8 bf[4][4];
    #pragma unroll
    for (int nt = 0; nt < 4; ++nt) {
        #pragma unroll
        for (int kt = 0; kt < 4; ++kt) {
            const float* wp = &W[(size_t)(nt * 16 + c) * 128 + kt * 32 + q * 8];
            float4 w0 = *(const float4*)wp;
            float4 w1 = *(const float4*)(wp + 4);
            bf16x8 f;
            f[0] = (short)bf16rne(w0.x); f[1] = (short)bf16rne(w0.y);
            f[2] = (short)bf16rne(w0.z); f[3] = (short)bf16rne(w0.w);
            f[4] = (short)bf16rne(w1.x); f[5] = (short)bf16rne(w1.y);
            f[6] = (short)bf16rne(w1.z); f[7] = (short)bf16rne(w1.w);
            bf[nt][kt] = f;
        }
    }
    float bias[4];
    #pragma unroll
    for (int nt = 0; nt < 4; ++nt) bias[nt] = b[nt * 16 + c];

    int oc = *ovfcnt; if (oc > ovfcap) oc = ovfcap;

    int gwave = blockIdx.x * 4 + wave;
    int nwave = gridDim.x * 4;
    int ntiles = (N + 15) >> 4;

    for (int tile = gwave; tile < ntiles; tile += nwave) {
        int n0 = tile << 4;
        int nm = n0 + c;
        int nmc = nm < N ? nm : N - 1;
        int deg = cnt[nmc];
        int extra = 0;
        if (oc > 0) {
            for (int t = 0; t < oc; ++t)
                if (ovf[2 * t] == nm) extra++;
        }
        int dtot = deg + extra;
        float inv = 1.0f / fmaxf((float)dtot, 1.0f);

        bf16x8 a0 = *(const bf16x8*)&hbs[(size_t)nmc * DF + q * 8];
        bf16x8 a1 = *(const bf16x8*)&hbs[(size_t)nmc * DF + 32 + q * 8];
        bf16x8 a2, a3;
        #pragma unroll
        for (int kc = 0; kc < 2; ++kc) {
            bf16x8 u = *(const bf16x8*)&csum[(size_t)nmc * DF + kc * 32 + q * 8];
            float e[8];
            #pragma unroll
            for (int i = 0; i < 8; ++i) e[i] = b2f((unsigned short)u[i]);
            if (oc > 0) {
                for (int t = 0; t < oc; ++t) {
                    if (ovf[2 * t] == nm) {
                        bf16x8 hu = *(const bf16x8*)&hbs[(size_t)ovf[2 * t + 1] * DF + kc * 32 + q * 8];
                        #pragma unroll
                        for (int i = 0; i < 8; ++i) e[i] += b2f((unsigned short)hu[i]);
                    }
                }
            }
            bf16x8 f;
            #pragma unroll
            for (int i = 0; i < 8; ++i) f[i] = (short)bf16rne(e[i] * inv);
            if (kc == 0) a2 = f; else a3 = f;
        }

        f32x4 acc0 = {bias[0], bias[0], bias[0], bias[0]};
        f32x4 acc1 = {bias[1], bias[1], bias[1], bias[1]};
        f32x4 acc2 = {bias[2], bias[2], bias[2], bias[2]};
        f32x4 acc3 = {bias[3], bias[3], bias[3], bias[3]};
        acc0 = __builtin_amdgcn_mfma_f32_16x16x32_bf16(a0, bf[0][0], acc0, 0, 0, 0);
        acc0 = __builtin_amdgcn_mfma_f32_16x16x32_bf16(a1, bf[0][1], acc0, 0, 0, 0);
        acc0 = __builtin_amdgcn_mfma_f32_16x16x32_bf16(a2, bf[0][2], acc0, 0, 0, 0);
        acc0 = __builtin_amdgcn_mfma_f32_16x16x32_bf16(a3, bf[0][3], acc0, 0, 0, 0);
        acc1 = __builtin_amdgcn_mfma_f32_16x16x32_bf16(a0, bf[1][0], acc1, 0, 0, 0);
        acc1 = __builtin_amdgcn_mfma_f32_16x16x32_bf16(a1, bf[1][1], acc1, 0, 0, 0);
        acc1 = __builtin_amdgcn_mfma_f32_16x16x32_bf16(a2, bf[1][2], acc1, 0, 0, 0);
        acc1 = __builtin_amdgcn_mfma_f32_16x16x32_bf16(a3, bf[1][3], acc1, 0, 0, 0);
        acc2 = __builtin_amdgcn_mfma_f32_16x16x32_bf16(a0, bf[2][0], acc2, 0, 0, 0);
        acc2 = __builtin_amdgcn_mfma_f32_16x16x32_bf16(a1, bf[2][1], acc2, 0, 0, 0);
        acc2 = __builtin_amdgcn_mfma_f32_16x16x32_bf16(a2, bf[2][2], acc2, 0, 0, 0);
        acc2 = __builtin_amdgcn_mfma_f32_16x16x32_bf16(a3, bf[2][3], acc2, 0, 0, 0);
        acc3 = __builtin_amdgcn_mfma_f32_16x16x32_bf16(a0, bf[3][0], acc3, 0, 0, 0);
        acc3 = __builtin_amdgcn_mfma_f32_16x16x32_bf16(a1, bf[3][1], acc3, 0, 0, 0);
        acc3 = __builtin_amdgcn_mfma_f32_16x16x32_bf16(a2, bf[3][2], acc3, 0, 0, 0);
        acc3 = __builtin_amdgcn_mfma_f32_16x16x32_bf16(a3, bf[3][3], acc3, 0, 0, 0);

        float ss[4];
        #pragma unroll
        for (int r = 0; r < 4; ++r)
            ss[r] = acc0[r] * acc0[r] + acc1[r] * acc1[r]
                  + acc2[r] * acc2[r] + acc3[r] * acc3[r];
        #pragma unroll
        for (int msk = 1; msk <= 8; msk <<= 1) {
            ss[0] += __shfl_xor(ss[0], msk);
            ss[1] += __shfl_xor(ss[1], msk);
            ss[2] += __shfl_xor(ss[2], msk);
            ss[3] += __shfl_xor(ss[3], msk);
        }
        #pragma unroll
        for (int r = 0; r < 4; ++r) {
            int nr = n0 + q * 4 + r;
            int dr = __shfl(deg + extra, q * 4 + r);
            if (nr < N) {
                float rin = 1.0f / fmaxf(sqrtf(ss[r]), 1e-12f);
                const float* hp = &h[(size_t)nr * DF + c];
                float hv0 = hp[0], hv1 = hp[16], hv2 = hp[32], hv3 = hp[48];
                bool up = dr > 0;
                float o0 = hv0 + (up ? fmaxf(acc0[r] * rin, 0.f) : hv0);
                float o1 = hv1 + (up ? fmaxf(acc1[r] * rin, 0.f) : hv1);
                float o2 = hv2 + (up ? fmaxf(acc2[r] * rin, 0.f) : hv2);
                float o3 = hv3 + (up ? fmaxf(acc3[r] * rin, 0.f) : hv3);
                float* op = &out[(size_t)nr * DF + c];
                op[0] = o0; op[16] = o1; op[32] = o2; op[48] = o3;
            }
        }
    }
}

extern "C" void kernel_launch(void* const* d_in, const int* in_sizes, int n_in,
                              void* d_out, int out_size, void* d_ws, size_t ws_size,
                              hipStream_t stream) {
    const float* h   = (const float*)d_in[0];
    const float* W   = (const float*)d_in[1];
    const float* b   = (const float*)d_in[2];
    const int*   src = (const int*)d_in[3];
    const int*   dst = (const int*)d_in[4];
    float* out = (float*)d_out;

    const int N = in_sizes[0] / DF;
    const int E = in_sizes[3];

    // workspace carve (16B-aligned); hbs has N+1 rows (zero sentinel)
    int* cnt    = (int*)d_ws;                               // N
    int* ovfcnt = cnt + N;                                  // 1
    int* gcur   = cnt + ((N + 31) & ~15);                   // NBB
    unsigned short* hbs  = (unsigned short*)(gcur + ((NBB + 15) & ~15));      // (N+1)*64
    unsigned short* csum = hbs + (((size_t)(N + 1) * DF + 15) & ~(size_t)15); // N*64
    unsigned* pairs = (unsigned*)(csum + (((size_t)N * DF + 15) & ~(size_t)15));
    int* ovf    = (int*)(pairs + (size_t)NBB * BSTR);
    size_t used = (size_t)((char*)ovf - (char*)d_ws);
    int ovfcap  = (ws_size > used + 64) ? (int)((ws_size - used) / 8 - 4) : 0;

    // K1: bf16 row-major conversion + zero row + cursor zeroing
    conv_zero<<<((N + 1) * 8 + 255) / 256, 256, 0, stream>>>(h, hbs, gcur, ovfcnt, N);

    // K2a: bin edges into 256 dst-range buckets (streaming writes)
    bin_edges<<<(E + EPT * 256 - 1) / (EPT * 256), 256, 0, stream>>>(
        src, dst, gcur, pairs, ovf, ovfcnt, ovfcap, E, N);

    // K2b: fused LDS-ELL build (quarter-bucket filter) + row-per-edge gather
    build_gather<<<NBB * GQ, 512, 0, stream>>>(
        pairs, gcur, hbs, cnt, csum, ovf, ovfcnt, ovfcap, N);

    // K4: MFMA update
    sage_update_mfma<<<512, 256, 0, stream>>>(
        h, W, b, cnt, hbs, csum, ovf, ovfcnt, ovfcap, out, N);
}